// Round 8
// baseline (371.491 us; speedup 1.0000x reference)
//
#include <hip/hip_runtime.h>
#include <hip/hip_bf16.h>

// Problem constants
#define B_    512
#define HIST_ 8
#define PRED_ 24
#define CITY_ 184
#define FEAT_ 13
#define HID_  32
#define BC_   (B_*CITY_)   // 94208 = 1472 * 64
#define FLAG_OFF 7168

// ws (float) layout (written by prep_all; rows PERMUTED, see below):
//   [0..4095]      Wh2[p*32+k] : W_hh + a0 (x) W_out   (t>=1 path)
//   [4096..6143]   Wf [p*16+f] : f<13: W_x[:,1+f]; f==13: bg2 (bias column,
//                                feature elem 13 is constant 1.0); f=14,15: 0
//   [6272..6399]   a0 [p]      : W_x[:,0]              (t==0)
//   [6528..6559]   wout[u]     : unit-indexed (NOT permuted)
//   [6560]         bout
//   [7168]         dtype flag: 0.0f = bf16 inputs, 1.0f = fp32 inputs
//
// Row permutation: original gate-row j = 32*gate + u (gate 0..3 = i,f,g,o,
// unit u 0..31) is stored at p = 16*tt + 4*(u>>3) + (psi&3), where
// psi = u&7, tt = 2*gate + (psi>>2).  The 16x16 MFMA D-tile at lane
// (rho=lane&15, q=lane>>4) then holds the complete i/f/g/o set for units
// {8q..8q+7} of seq rho == exactly the B-fragment k-slice (k=8q+elem) the
// lane must supply next step.  h never leaves the lane; no LDS at all.
//
// NOTE (R4): VGPR cap < working set -> spill catastrophe (FETCH 60MB->1.3GB).
// NOTE (R5): s_setprio corrupted results in the clean build.  Never again.
// NOTE (R6): quad-rcp/inv4 + clamps REGRESSED.  Plain sigf/tanhf_ wins.
// NOTE (R8): feature-part k16 MFMAs for step t+1 are hoisted into step t
// (software pipeline): they run on the matrix pipe while finish(t) runs on
// VALU/trans -> the per-step serial chain is only k32 -> finish -> pack.

struct TrueT  { static constexpr bool value = true;  };
struct FalseT { static constexpr bool value = false; };

typedef _Float16 v8hf __attribute__((ext_vector_type(8)));
typedef _Float16 v4hf __attribute__((ext_vector_type(4)));
typedef _Float16 v2hf __attribute__((ext_vector_type(2)));
typedef float    v4f  __attribute__((ext_vector_type(4)));

// __builtin_amdgcn_cvt_pkrtz returns __fp16x2; bit-identical to _Float16x2.
__device__ __forceinline__ v2hf pkrtz(float a, float b) {
    return __builtin_bit_cast(v2hf, __builtin_amdgcn_cvt_pkrtz(a, b));
}

__device__ __forceinline__ float rcp_(float x) { return __builtin_amdgcn_rcpf(x); }
__device__ __forceinline__ float sigf(float x) { return rcp_(1.0f + __expf(-x)); }
__device__ __forceinline__ float tanhf_(float x) {
    float e = __expf(2.0f * x);
    return 1.0f - 2.0f * rcp_(e + 1.0f);   // saturates correctly (rcp(inf)=0)
}

template<bool F32>
__device__ __forceinline__ float ldin(const void* p, long i) {
    if constexpr (F32) return ((const float*)p)[i];
    else               return __bfloat162float(((const __hip_bfloat16*)p)[i]);
}
template<bool F32>
__device__ __forceinline__ void stout(void* p, long i, float v) {
    if constexpr (F32) ((float*)p)[i] = v;
    else               ((__hip_bfloat16*)p)[i] = __float2bfloat16(v);
}

// MFMA wrappers. K16 legacy builtin guarded: the K32 fallback with zero-padded
// element slots is exactly equivalent (A/B share the (lane,elem)->k labeling).
__device__ __forceinline__ v4f mfma_k32(v8hf a, v8hf b, v4f c) {
    return __builtin_amdgcn_mfma_f32_16x16x32_f16(a, b, c, 0, 0, 0);
}
__device__ __forceinline__ v4f mfma_k16(v4hf a, v4hf b, v4f c) {
#if __has_builtin(__builtin_amdgcn_mfma_f32_16x16x16f16)
    return __builtin_amdgcn_mfma_f32_16x16x16f16(a, b, c, 0, 0, 0);
#else
    v8hf a8; v8hf b8;
    #pragma unroll
    for (int j = 0; j < 4; ++j) { a8[j] = a[j]; b8[j] = b[j]; }
    #pragma unroll
    for (int j = 4; j < 8; ++j) { a8[j] = (_Float16)0.f; b8[j] = (_Float16)0.f; }
    return __builtin_amdgcn_mfma_f32_16x16x32_f16(a8, b8, c, 0, 0, 0);
#endif
}

// ---- prep body (templated on dtype), writes permuted rows ----
template<bool F32>
__device__ __forceinline__ void prep_body(const void* W_in, const void* b_in,
                                          const void* W_out, const void* b_out,
                                          const void* W_ih, const void* W_hh,
                                          const void* b_ih, const void* b_hh,
                                          float* ws, int j)
{
    if (j >= 128) return;
    // original gate-row j -> permuted position p
    const int gate = j >> 5;
    const int u    = j & 31;
    const int qb   = u >> 3;
    const int psi  = u & 7;
    const int tt   = 2*gate + (psi >> 2);
    const int p    = 16*tt + 4*qb + (psi & 3);

    float wx[14];
    #pragma unroll
    for (int c = 0; c < 14; ++c) wx[c] = 0.0f;
    float bg = ldin<F32>(b_ih, j) + ldin<F32>(b_hh, j);
    #pragma unroll
    for (int m = 0; m < 32; ++m) {
        float wihm = ldin<F32>(W_ih, j*32 + m);
        #pragma unroll
        for (int c = 0; c < 14; ++c) wx[c] = fmaf(wihm, ldin<F32>(W_in, m*14 + c), wx[c]);
        bg = fmaf(wihm, ldin<F32>(b_in, m), bg);
    }
    float a0 = wx[0];
    #pragma unroll
    for (int k = 0; k < 32; ++k)
        ws[p*32 + k] = ldin<F32>(W_hh, j*32 + k) + a0 * ldin<F32>(W_out, k);
    #pragma unroll
    for (int f = 0; f < 13; ++f) ws[4096 + p*16 + f] = wx[1 + f];
    float bo = ldin<F32>(b_out, 0);
    const float bg2 = bg + a0 * bo;
    ws[4096 + p*16 + 13] = bg2;    // bias column: feature elem 13 loads 1.0
    ws[4096 + p*16 + 14] = 0.0f;   // pad (never poison)
    ws[4096 + p*16 + 15] = 0.0f;
    ws[6272 + p] = a0;
    if (j < 32) ws[6528 + j] = ldin<F32>(W_out, j);   // unit-indexed, unpermuted
    if (j == 0) ws[6560] = bo;
}

// ---- fused detect + prep: one launch ----
__global__ void prep_all(const unsigned short* __restrict__ feat_raw,
                         const void* __restrict__ W_in,  const void* __restrict__ b_in,
                         const void* __restrict__ W_out, const void* __restrict__ b_out,
                         const void* __restrict__ W_ih,  const void* __restrict__ W_hh,
                         const void* __restrict__ b_ih,  const void* __restrict__ b_hh,
                         float* __restrict__ ws)
{
    __shared__ int cnt;
    const int tid = threadIdx.x;   // 0..127
    if (tid == 0) cnt = 0;
    __syncthreads();
    int insane = 0;
    for (int i = tid; i < 4096; i += 128) {
        float v = __uint_as_float(((unsigned int)feat_raw[i]) << 16);
        if (!(fabsf(v) < 1e8f)) insane++;
    }
    if (insane) atomicAdd(&cnt, insane);
    __syncthreads();
    const bool f32 = (cnt > 8);
    if (tid == 0) ws[FLAG_OFF] = f32 ? 1.0f : 0.0f;
    if (f32) prep_body<true >(W_in,b_in,W_out,b_out,W_ih,W_hh,b_ih,b_hh,ws,tid);
    else     prep_body<false>(W_in,b_in,W_out,b_out,W_ih,W_hh,b_ih,b_hh,ws,tid);
}

// ---- main LSTM body: zero LDS, h recirculates in-register ----
// F32=false (bf16 inputs): LEAN path (no lo-compensation; err ~3e-4 vs 3.2e-3).
// F32=true: full fp16 hi/lo split (fp32-equivalent accuracy).
template<bool F32>
__device__ __forceinline__ void lstm_body(const void* __restrict__ pm25,
                                          const void* __restrict__ feat,
                                          const float* __restrict__ ws,
                                          void* __restrict__ out)
{
    const int lane = threadIdx.x & 63;
    const int rho  = lane & 15;      // seq within wave / A-row / D-col
    const int q    = lane >> 4;      // k-block / D-row-block / unit-block
    const int wv   = threadIdx.x >> 6;
    const int wseq = (blockIdx.x*4 + wv) * 16;
    const int seq  = wseq + rho;
    const int bb   = seq / CITY_;
    const int city = seq - bb*CITY_;

    // ---- weights -> fp16 A-fragments (once per wave) ----
    v8hf Whi0[8]; v4hf Whi1[8];
    v8hf Wlo0[8]; v4hf Wlo1[8];      // used only when F32 (constexpr-dead)
    #pragma unroll
    for (int tt = 0; tt < 8; ++tt) {
        const float* wr = ws + (16*tt + rho)*32 + 8*q;
        #pragma unroll
        for (int j = 0; j < 8; ++j) {
            const float w = wr[j];
            const _Float16 h = (_Float16)w;
            Whi0[tt][j] = h;
            if constexpr (F32) Wlo0[tt][j] = (_Float16)(w - (float)h);
        }
        const float* wf = ws + 4096 + (16*tt + rho)*16 + 4*q;
        #pragma unroll
        for (int j = 0; j < 4; ++j) {
            const float w = wf[j];
            const _Float16 h = (_Float16)w;
            Whi1[tt][j] = h;
            if constexpr (F32) Wlo1[tt][j] = (_Float16)(w - (float)h);
        }
    }
    float wo8[8];
    #pragma unroll
    for (int j = 0; j < 8; ++j) wo8[j] = ws[6528 + 8*q + j]; // wout[unit 8q+j]
    const float bo = ws[6560];
    const long obase = (long)bb*PRED_*CITY_ + city;

    // ---- per-lane direct feature loads (no LDS): elems 4q..4q+3.
    // elem 13 = constant 1.0 (bias column); 14,15 = 0.
    long fbase = ((long)(bb*(HIST_+PRED_) + HIST_)*CITY_ + city)*FEAT_;
    float fn[4];
    auto ldfeat = [&]() {            // prefetch one step's 4 elems into regs
        #pragma unroll
        for (int j = 0; j < 4; ++j) {
            const int e = 4*q + j;
            fn[j] = (e < FEAT_) ? ldin<F32>(feat, fbase + e)
                                : (e == FEAT_ ? 1.0f : 0.0f);
        }
        fbase += CITY_ * FEAT_;
    };
    v4hf fhi, flo;
    auto convf = [&]() {             // fn (raw) -> fp16 fragment(s)
        #pragma unroll
        for (int jj = 0; jj < 2; ++jj) {
            const v2hf ph = pkrtz(fn[2*jj], fn[2*jj+1]);
            fhi[2*jj] = ph[0]; fhi[2*jj+1] = ph[1];
            if constexpr (F32) {
                const v2hf pl = pkrtz(fn[2*jj] - (float)ph[0],
                                      fn[2*jj+1] - (float)ph[1]);
                flo[2*jj] = pl[0]; flo[2*jj+1] = pl[1];
            }
        }
    };

    const v4f zacc = {0.0f, 0.0f, 0.0f, 0.0f};
    v4f facc[8];                     // NEXT step's feature+bias gate part
    auto buildfeat = [&]() {         // facc = Wf . [feat;1]  (k16 MFMAs)
        #pragma unroll
        for (int tt = 0; tt < 8; ++tt) {
            v4f a = mfma_k16(Whi1[tt], fhi, zacc);
            if constexpr (F32) {
                a = mfma_k16(Wlo1[tt], fhi, a);
                a = mfma_k16(Whi1[tt], flo, a);
            }
            facc[tt] = a;
        }
    };

    float cst[8];                    // c-state, units 8q+psi, seq rho
    v8hf  xhi, xlo;                  // h: next step's B chunk0 (in-lane!)

    auto finishT = [&](v4f (&acc)[8], int t, auto T0flag) {
        constexpr bool T0 = decltype(T0flag)::value;
        // psi = 4*(tt&1)+r: i=acc[tl], f=acc[2+tl], g=acc[4+tl], o=acc[6+tl]
        float h[8];
        #pragma unroll
        for (int psi = 0; psi < 8; ++psi) {
            const int tl = psi >> 2, r = psi & 3;
            const float I = sigf(acc[tl][r]);
            const float G = tanhf_(acc[4+tl][r]);
            const float O = sigf(acc[6+tl][r]);
            float c;
            if constexpr (T0) c = I*G;
            else              c = fmaf(sigf(acc[2+tl][r]), cst[psi], I*G);
            cst[psi] = c;
            h[psi] = O * tanhf_(c);
        }
        #pragma unroll
        for (int jj = 0; jj < 4; ++jj) {   // pack -> next B fragment
            const v2hf ph = pkrtz(h[2*jj], h[2*jj+1]);
            xhi[2*jj] = ph[0]; xhi[2*jj+1] = ph[1];
            if constexpr (F32) {           // lo exactly compensates RTZ
                const v2hf pl = pkrtz(h[2*jj] - (float)ph[0],
                                      h[2*jj+1] - (float)ph[1]);
                xlo[2*jj] = pl[0]; xlo[2*jj+1] = pl[1];
            }
        }
        float y = 0.0f;                    // y_t = wout . h + bout
        #pragma unroll
        for (int psi = 0; psi < 8; ++psi) y = fmaf(wo8[psi], h[psi], y);
        y += __shfl_xor(y, 16);
        y += __shfl_xor(y, 32);
        if (q == 0) stout<F32>(out, obase + (long)t*CITY_, y + bo);
    };

    // ---- t = 0 : gates = a0*(x0-bo) (C-init) + Wf.[feat;1]  (h0 = 0) ----
    ldfeat();            // fn = feats(0)
    convf();             // fhi = feats(0)
    ldfeat();            // fn = feats(1) in flight
    v4f acc0[8];
    {
        const float x0 = ldin<F32>(pm25, (long)(bb*HIST_ + (HIST_-1))*CITY_ + city);
        const float x0b = x0 - bo;
        #pragma unroll
        for (int tt = 0; tt < 8; ++tt) {
            const v4f a0 = *(const v4f*)(ws + 6272 + 16*tt + 4*q);
            v4f c;
            #pragma unroll
            for (int r = 0; r < 4; ++r) c[r] = a0[r] * x0b;
            v4f a = mfma_k16(Whi1[tt], fhi, c);
            if constexpr (F32) {
                a = mfma_k16(Wlo1[tt], fhi, a);
                a = mfma_k16(Whi1[tt], flo, a);
            }
            acc0[tt] = a;
        }
    }
    // pipeline: build facc for t=1 (matrix pipe) before/while finishing t=0
    convf();             // fhi = feats(1)
    ldfeat();            // fn = feats(2) in flight
    buildfeat();
    finishT(acc0, 0, TrueT{});

    // ---- t = 1..23 : acc = Wh2.h (k32) + facc; facc(t+1) overlaps finish ----
    #pragma unroll 1
    for (int t = 1; t < PRED_; ++t) {
        v4f acc[8];
        #pragma unroll
        for (int tt = 0; tt < 8; ++tt) {
            v4f a = mfma_k32(Whi0[tt], xhi, facc[tt]);
            if constexpr (F32) {
                a = mfma_k32(Wlo0[tt], xhi, a);
                a = mfma_k32(Whi0[tt], xlo, a);
            }
            acc[tt] = a;
        }
        if (t < PRED_-1) {
            convf();                    // fhi = feats(t+1)
            if (t < PRED_-2) ldfeat();  // fn = feats(t+2), guard OOB
            buildfeat();                // matrix pipe, overlaps finish below
        }
        finishT(acc, t, FalseT{});
    }
}

// bf16 kernel: lean register set -> cap 170 (3 waves/EU) is spill-safe.
__global__ __launch_bounds__(256, 3) void lstm_bf16(
    const void* __restrict__ pm25, const void* __restrict__ feat,
    const float* __restrict__ ws,  void* __restrict__ out)
{
    if (ws[FLAG_OFF] != 0.0f) return;
    lstm_body<false>(pm25, feat, ws, out);
}

// fp32 kernel: full hi/lo set -> keep cap 256.
__global__ __launch_bounds__(256, 2) void lstm_f32(
    const void* __restrict__ pm25, const void* __restrict__ feat,
    const float* __restrict__ ws,  void* __restrict__ out)
{
    if (ws[FLAG_OFF] != 1.0f) return;
    lstm_body<true>(pm25, feat, ws, out);
}

extern "C" void kernel_launch(void* const* d_in, const int* in_sizes, int n_in,
                              void* d_out, int out_size, void* d_ws, size_t ws_size,
                              hipStream_t stream) {
    const void* pm25  = d_in[0];
    const void* feat  = d_in[1];
    const void* W_in  = d_in[2];
    const void* b_in  = d_in[3];
    const void* W_out = d_in[4];
    const void* b_out = d_in[5];
    const void* W_ih  = d_in[6];
    const void* W_hh  = d_in[7];
    const void* b_ih  = d_in[8];
    const void* b_hh  = d_in[9];
    float* ws = (float*)d_ws;

    prep_all<<<dim3(1), dim3(128), 0, stream>>>(
        (const unsigned short*)feat, W_in, b_in, W_out, b_out,
        W_ih, W_hh, b_ih, b_hh, ws);

    lstm_bf16<<<dim3(BC_/64), dim3(256), 0, stream>>>(pm25, feat, ws, d_out);
    lstm_f32 <<<dim3(BC_/64), dim3(256), 0, stream>>>(pm25, feat, ws, d_out);
}

// Round 9
// 349.994 us; speedup vs baseline: 1.0614x; 1.0614x over previous
//
#include <hip/hip_runtime.h>
#include <hip/hip_bf16.h>

// Problem constants
#define B_    512
#define HIST_ 8
#define PRED_ 24
#define CITY_ 184
#define FEAT_ 13
#define HID_  32
#define BC_   (B_*CITY_)   // 94208 = 1472 * 64
#define FLAG_OFF 7168

// ws (float) layout (written by prep_all; rows PERMUTED, see below):
//   [0..4095]      Wh2[p*32+k] : W_hh + a0 (x) W_out   (t>=1 path)
//   [4096..6143]   Wf [p*16+f] : f<13: W_x[:,1+f]; f==13: bg2 (bias column,
//                                feature elem 13 is constant 1.0); f=14,15: 0
//   [6272..6399]   a0 [p]      : W_x[:,0]              (t==0)
//   [6528..6559]   wout[u]     : unit-indexed (NOT permuted)
//   [6560]         bout
//   [7168]         dtype flag: 0.0f = bf16 inputs, 1.0f = fp32 inputs
//
// Row permutation: original gate-row j = 32*gate + u (gate 0..3 = i,f,g,o,
// unit u 0..31) is stored at p = 16*tt + 4*(u>>3) + (psi&3), where
// psi = u&7, tt = 2*gate + (psi>>2).  The 16x16 MFMA D-tile at lane
// (rho=lane&15, q=lane>>4) then holds the complete i/f/g/o set for units
// {8q..8q+7} of seq rho == exactly the B-fragment k-slice (k=8q+elem) the
// lane must supply next step.  h never leaves the lane; no LDS at all.
//
// NOTE (R4): VGPR cap < working set -> spill catastrophe (FETCH 60MB->1.3GB).
// NOTE (R5): s_setprio corrupted results in the clean build.  Never again.
// NOTE (R6): quad-rcp/inv4 + clamps REGRESSED.  Plain sigf/tanhf_ wins.
// NOTE (R8): facc software-pipeline REGRESSED (occ 27->20).  Reverted.
// NOTE (R9): R7's VGPR=84 < declared ~190-reg working set with zero scratch
// => compiler REMATERIALIZED weights every step (reload f32 + re-convert,
// ~300 VALU/step invisible in source).  keep() pins the converted fragments
// (opaque asm producer) so they stay register-resident.

struct TrueT  { static constexpr bool value = true;  };
struct FalseT { static constexpr bool value = false; };

typedef _Float16 v8hf __attribute__((ext_vector_type(8)));
typedef _Float16 v4hf __attribute__((ext_vector_type(4)));
typedef _Float16 v2hf __attribute__((ext_vector_type(2)));
typedef float    v4f  __attribute__((ext_vector_type(4)));

// Opaque producer: compiler cannot rematerialize x past this point, so it
// must keep x live in VGPRs (cheap keep-alive, no code emitted).
template<typename T>
__device__ __forceinline__ void keep(T& x) { asm volatile("" : "+v"(x)); }

// __builtin_amdgcn_cvt_pkrtz returns __fp16x2; bit-identical to _Float16x2.
__device__ __forceinline__ v2hf pkrtz(float a, float b) {
    return __builtin_bit_cast(v2hf, __builtin_amdgcn_cvt_pkrtz(a, b));
}

__device__ __forceinline__ float rcp_(float x) { return __builtin_amdgcn_rcpf(x); }
__device__ __forceinline__ float sigf(float x) { return rcp_(1.0f + __expf(-x)); }
__device__ __forceinline__ float tanhf_(float x) {
    float e = __expf(2.0f * x);
    return 1.0f - 2.0f * rcp_(e + 1.0f);   // saturates correctly (rcp(inf)=0)
}

template<bool F32>
__device__ __forceinline__ float ldin(const void* p, long i) {
    if constexpr (F32) return ((const float*)p)[i];
    else               return __bfloat162float(((const __hip_bfloat16*)p)[i]);
}
template<bool F32>
__device__ __forceinline__ void stout(void* p, long i, float v) {
    if constexpr (F32) ((float*)p)[i] = v;
    else               ((__hip_bfloat16*)p)[i] = __float2bfloat16(v);
}

// MFMA wrappers. K16 legacy builtin guarded: the K32 fallback with zero-padded
// element slots is exactly equivalent (A/B share the (lane,elem)->k labeling).
__device__ __forceinline__ v4f mfma_k32(v8hf a, v8hf b, v4f c) {
    return __builtin_amdgcn_mfma_f32_16x16x32_f16(a, b, c, 0, 0, 0);
}
__device__ __forceinline__ v4f mfma_k16(v4hf a, v4hf b, v4f c) {
#if __has_builtin(__builtin_amdgcn_mfma_f32_16x16x16f16)
    return __builtin_amdgcn_mfma_f32_16x16x16f16(a, b, c, 0, 0, 0);
#else
    v8hf a8; v8hf b8;
    #pragma unroll
    for (int j = 0; j < 4; ++j) { a8[j] = a[j]; b8[j] = b[j]; }
    #pragma unroll
    for (int j = 4; j < 8; ++j) { a8[j] = (_Float16)0.f; b8[j] = (_Float16)0.f; }
    return __builtin_amdgcn_mfma_f32_16x16x32_f16(a8, b8, c, 0, 0, 0);
#endif
}

// ---- prep body (templated on dtype), writes permuted rows ----
template<bool F32>
__device__ __forceinline__ void prep_body(const void* W_in, const void* b_in,
                                          const void* W_out, const void* b_out,
                                          const void* W_ih, const void* W_hh,
                                          const void* b_ih, const void* b_hh,
                                          float* ws, int j)
{
    if (j >= 128) return;
    // original gate-row j -> permuted position p
    const int gate = j >> 5;
    const int u    = j & 31;
    const int qb   = u >> 3;
    const int psi  = u & 7;
    const int tt   = 2*gate + (psi >> 2);
    const int p    = 16*tt + 4*qb + (psi & 3);

    float wx[14];
    #pragma unroll
    for (int c = 0; c < 14; ++c) wx[c] = 0.0f;
    float bg = ldin<F32>(b_ih, j) + ldin<F32>(b_hh, j);
    #pragma unroll
    for (int m = 0; m < 32; ++m) {
        float wihm = ldin<F32>(W_ih, j*32 + m);
        #pragma unroll
        for (int c = 0; c < 14; ++c) wx[c] = fmaf(wihm, ldin<F32>(W_in, m*14 + c), wx[c]);
        bg = fmaf(wihm, ldin<F32>(b_in, m), bg);
    }
    float a0 = wx[0];
    #pragma unroll
    for (int k = 0; k < 32; ++k)
        ws[p*32 + k] = ldin<F32>(W_hh, j*32 + k) + a0 * ldin<F32>(W_out, k);
    #pragma unroll
    for (int f = 0; f < 13; ++f) ws[4096 + p*16 + f] = wx[1 + f];
    float bo = ldin<F32>(b_out, 0);
    const float bg2 = bg + a0 * bo;
    ws[4096 + p*16 + 13] = bg2;    // bias column: feature elem 13 loads 1.0
    ws[4096 + p*16 + 14] = 0.0f;   // pad (never poison)
    ws[4096 + p*16 + 15] = 0.0f;
    ws[6272 + p] = a0;
    if (j < 32) ws[6528 + j] = ldin<F32>(W_out, j);   // unit-indexed, unpermuted
    if (j == 0) ws[6560] = bo;
}

// ---- fused detect + prep: one launch ----
__global__ void prep_all(const unsigned short* __restrict__ feat_raw,
                         const void* __restrict__ W_in,  const void* __restrict__ b_in,
                         const void* __restrict__ W_out, const void* __restrict__ b_out,
                         const void* __restrict__ W_ih,  const void* __restrict__ W_hh,
                         const void* __restrict__ b_ih,  const void* __restrict__ b_hh,
                         float* __restrict__ ws)
{
    __shared__ int cnt;
    const int tid = threadIdx.x;   // 0..127
    if (tid == 0) cnt = 0;
    __syncthreads();
    int insane = 0;
    for (int i = tid; i < 4096; i += 128) {
        float v = __uint_as_float(((unsigned int)feat_raw[i]) << 16);
        if (!(fabsf(v) < 1e8f)) insane++;
    }
    if (insane) atomicAdd(&cnt, insane);
    __syncthreads();
    const bool f32 = (cnt > 8);
    if (tid == 0) ws[FLAG_OFF] = f32 ? 1.0f : 0.0f;
    if (f32) prep_body<true >(W_in,b_in,W_out,b_out,W_ih,W_hh,b_ih,b_hh,ws,tid);
    else     prep_body<false>(W_in,b_in,W_out,b_out,W_ih,W_hh,b_ih,b_hh,ws,tid);
}

// ---- main LSTM body: zero LDS, h recirculates in-register ----
// F32=false (bf16 inputs): LEAN path (no lo-compensation; err ~3e-4 vs 3.2e-3).
// F32=true: full fp16 hi/lo split (fp32-equivalent accuracy).
template<bool F32>
__device__ __forceinline__ void lstm_body(const void* __restrict__ pm25,
                                          const void* __restrict__ feat,
                                          const float* __restrict__ ws,
                                          void* __restrict__ out)
{
    const int lane = threadIdx.x & 63;
    const int rho  = lane & 15;      // seq within wave / A-row / D-col
    const int q    = lane >> 4;      // k-block / D-row-block / unit-block
    const int wv   = threadIdx.x >> 6;
    const int wseq = (blockIdx.x*4 + wv) * 16;
    const int seq  = wseq + rho;
    const int bb   = seq / CITY_;
    const int city = seq - bb*CITY_;

    // ---- weights -> fp16 A-fragments (once per wave), PINNED in VGPRs ----
    v8hf Whi0[8]; v4hf Whi1[8];
    v8hf Wlo0[8]; v4hf Wlo1[8];      // used only when F32 (constexpr-dead)
    #pragma unroll
    for (int tt = 0; tt < 8; ++tt) {
        const float* wr = ws + (16*tt + rho)*32 + 8*q;
        #pragma unroll
        for (int j = 0; j < 8; ++j) {
            const float w = wr[j];
            const _Float16 h = (_Float16)w;
            Whi0[tt][j] = h;
            if constexpr (F32) Wlo0[tt][j] = (_Float16)(w - (float)h);
        }
        const float* wf = ws + 4096 + (16*tt + rho)*16 + 4*q;
        #pragma unroll
        for (int j = 0; j < 4; ++j) {
            const float w = wf[j];
            const _Float16 h = (_Float16)w;
            Whi1[tt][j] = h;
            if constexpr (F32) Wlo1[tt][j] = (_Float16)(w - (float)h);
        }
        keep(Whi0[tt]); keep(Whi1[tt]);
        if constexpr (F32) { keep(Wlo0[tt]); keep(Wlo1[tt]); }
    }
    float wo8[8];
    #pragma unroll
    for (int j = 0; j < 8; ++j) {
        wo8[j] = ws[6528 + 8*q + j]; // wout[unit 8q+j]
        keep(wo8[j]);
    }
    const float bo = ws[6560];
    const long obase = (long)bb*PRED_*CITY_ + city;

    // ---- per-lane direct feature loads (no LDS): elems 4q..4q+3.
    // elem 13 = constant 1.0 (bias column); 14,15 = 0.
    long fbase = ((long)(bb*(HIST_+PRED_) + HIST_)*CITY_ + city)*FEAT_;
    float fn[4];
    auto ldfeat = [&]() {            // prefetch one step's 4 elems into regs
        #pragma unroll
        for (int j = 0; j < 4; ++j) {
            const int e = 4*q + j;
            fn[j] = (e < FEAT_) ? ldin<F32>(feat, fbase + e)
                                : (e == FEAT_ ? 1.0f : 0.0f);
        }
        fbase += CITY_ * FEAT_;
    };
    v4hf fhi, flo;
    auto convf = [&]() {             // fn (raw) -> fp16 fragment(s)
        #pragma unroll
        for (int jj = 0; jj < 2; ++jj) {
            const v2hf ph = pkrtz(fn[2*jj], fn[2*jj+1]);
            fhi[2*jj] = ph[0]; fhi[2*jj+1] = ph[1];
            if constexpr (F32) {
                const v2hf pl = pkrtz(fn[2*jj] - (float)ph[0],
                                      fn[2*jj+1] - (float)ph[1]);
                flo[2*jj] = pl[0]; flo[2*jj+1] = pl[1];
            }
        }
    };

    float cst[8];                    // c-state, units 8q+psi, seq rho
    v8hf  xhi, xlo;                  // h: next step's B chunk0 (in-lane!)

    auto finishT = [&](v4f (&acc)[8], int t, auto T0flag) {
        constexpr bool T0 = decltype(T0flag)::value;
        // psi = 4*(tt&1)+r: i=acc[tl], f=acc[2+tl], g=acc[4+tl], o=acc[6+tl]
        float h[8];
        #pragma unroll
        for (int psi = 0; psi < 8; ++psi) {
            const int tl = psi >> 2, r = psi & 3;
            const float I = sigf(acc[tl][r]);
            const float G = tanhf_(acc[4+tl][r]);
            const float O = sigf(acc[6+tl][r]);
            float c;
            if constexpr (T0) c = I*G;
            else              c = fmaf(sigf(acc[2+tl][r]), cst[psi], I*G);
            cst[psi] = c;
            h[psi] = O * tanhf_(c);
        }
        #pragma unroll
        for (int jj = 0; jj < 4; ++jj) {   // pack -> next B fragment
            const v2hf ph = pkrtz(h[2*jj], h[2*jj+1]);
            xhi[2*jj] = ph[0]; xhi[2*jj+1] = ph[1];
            if constexpr (F32) {           // lo exactly compensates RTZ
                const v2hf pl = pkrtz(h[2*jj] - (float)ph[0],
                                      h[2*jj+1] - (float)ph[1]);
                xlo[2*jj] = pl[0]; xlo[2*jj+1] = pl[1];
            }
        }
        float y = 0.0f;                    // y_t = wout . h + bout
        #pragma unroll
        for (int psi = 0; psi < 8; ++psi) y = fmaf(wo8[psi], h[psi], y);
        y += __shfl_xor(y, 16);
        y += __shfl_xor(y, 32);
        if (q == 0) stout<F32>(out, obase + (long)t*CITY_, y + bo);
    };

    // ---- t = 0 : gates = a0*(x0-bo) (C-init) + Wf.[feat;1]  (h0 = 0) ----
    ldfeat();            // fn = feats(0)
    convf();             // fhi = feats(0)
    ldfeat();            // fn = feats(1) in flight
    {
        const float x0 = ldin<F32>(pm25, (long)(bb*HIST_ + (HIST_-1))*CITY_ + city);
        const float x0b = x0 - bo;
        v4f acc[8];
        #pragma unroll
        for (int tt = 0; tt < 8; ++tt) {
            const v4f a0 = *(const v4f*)(ws + 6272 + 16*tt + 4*q);
            v4f c;
            #pragma unroll
            for (int r = 0; r < 4; ++r) c[r] = a0[r] * x0b;
            v4f a = mfma_k16(Whi1[tt], fhi, c);
            if constexpr (F32) {
                a = mfma_k16(Wlo1[tt], fhi, a);
                a = mfma_k16(Whi1[tt], flo, a);
            }
            acc[tt] = a;
        }
        finishT(acc, 0, TrueT{});
    }

    // ---- t = 1..23 ----
    const v4f zacc = {0.0f, 0.0f, 0.0f, 0.0f};
    #pragma unroll 1
    for (int t = 1; t < PRED_; ++t) {
        convf();                        // fhi = feats(t) (loaded last iter)
        if (t < PRED_-1) ldfeat();      // fn = feats(t+1)
        v4f acc[8];
        #pragma unroll
        for (int tt = 0; tt < 8; ++tt) {
            v4f a = mfma_k32(Whi0[tt], xhi, zacc);
            if constexpr (F32) {
                a = mfma_k32(Wlo0[tt], xhi, a);
                a = mfma_k32(Whi0[tt], xlo, a);
            }
            a = mfma_k16(Whi1[tt], fhi, a);
            if constexpr (F32) {
                a = mfma_k16(Wlo1[tt], fhi, a);
                a = mfma_k16(Whi1[tt], flo, a);
            }
            acc[tt] = a;
        }
        finishT(acc, t, FalseT{});
    }
}

// bf16 kernel: pinned weights ~48 VGPRs + state -> cap 170 (3/EU) spill-safe.
__global__ __launch_bounds__(256, 3) void lstm_bf16(
    const void* __restrict__ pm25, const void* __restrict__ feat,
    const float* __restrict__ ws,  void* __restrict__ out)
{
    if (ws[FLAG_OFF] != 0.0f) return;
    lstm_body<false>(pm25, feat, ws, out);
}

// fp32 kernel: pinned hi/lo set ~112 VGPRs + state -> keep cap 256.
__global__ __launch_bounds__(256, 2) void lstm_f32(
    const void* __restrict__ pm25, const void* __restrict__ feat,
    const float* __restrict__ ws,  void* __restrict__ out)
{
    if (ws[FLAG_OFF] != 1.0f) return;
    lstm_body<true>(pm25, feat, ws, out);
}

extern "C" void kernel_launch(void* const* d_in, const int* in_sizes, int n_in,
                              void* d_out, int out_size, void* d_ws, size_t ws_size,
                              hipStream_t stream) {
    const void* pm25  = d_in[0];
    const void* feat  = d_in[1];
    const void* W_in  = d_in[2];
    const void* b_in  = d_in[3];
    const void* W_out = d_in[4];
    const void* b_out = d_in[5];
    const void* W_ih  = d_in[6];
    const void* W_hh  = d_in[7];
    const void* b_ih  = d_in[8];
    const void* b_hh  = d_in[9];
    float* ws = (float*)d_ws;

    prep_all<<<dim3(1), dim3(128), 0, stream>>>(
        (const unsigned short*)feat, W_in, b_in, W_out, b_out,
        W_ih, W_hh, b_ih, b_hh, ws);

    lstm_bf16<<<dim3(BC_/64), dim3(256), 0, stream>>>(pm25, feat, ws, d_out);
    lstm_f32 <<<dim3(BC_/64), dim3(256), 0, stream>>>(pm25, feat, ws, d_out);
}

// Round 11
// 333.789 us; speedup vs baseline: 1.1130x; 1.0486x over previous
//
#include <hip/hip_runtime.h>
#include <hip/hip_bf16.h>

// Problem constants
#define B_    512
#define HIST_ 8
#define PRED_ 24
#define CITY_ 184
#define FEAT_ 13
#define HID_  32
#define BC_   (B_*CITY_)   // 94208 = 1472 * 64
#define FLAG_OFF 7168

// ws (float) layout (written by prep_all; rows PERMUTED, see below):
//   [0..4095]      Wh2[p*32+k] : W_hh + a0 (x) W_out   (t>=1 path)
//   [4096..6143]   Wf [p*16+f] : f<13: W_x[:,1+f]; f==13: bg2 (bias column,
//                                feature elem 13 is constant 1.0); f=14,15: 0
//   [6272..6399]   a0 [p]      : W_x[:,0]              (t==0)
//   [6528..6559]   wout[u]     : unit-indexed
//   [6560]         bout
//   [7168]         dtype flag: 0.0f = bf16 inputs, 1.0f = fp32 inputs
//
// *** WS BUDGET RULE (R10 post-mortem): never write ws beyond index 7168.
// R10 put packed fragments at float idx 8192..14335 -> OOB (workspace is
// ~8192 floats; FLAG at 7168 was chosen to fit).  Writes corrupted adjacent
// memory: bf16 absmax 6.1e-3, f32 poison 468.  Fragment cache now lives in
// per-block LDS instead. ***
//
// Row permutation: gate-row j = 32*gate + u stored at p = 16*tt + 4*(u>>3)
// + (psi&3), psi = u&7, tt = 2*gate + (psi>>2).  D-tile at lane (rho,q)
// holds i/f/g/o of units {8q..8q+7}, seq rho == the B k-slice the lane
// supplies next step.  h never leaves the lane.
//
// NOTE (R4): VGPR cap < working set -> spill catastrophe. Keep caps generous.
// NOTE (R5): s_setprio corrupted results.  Never again.
// NOTE (R6): quad-rcp/inv4 regressed.  Plain sigf/tanhf_.
// NOTE (R8): facc software-pipeline regressed.  Reverted.
// NOTE (R9): keep()-pinning was NULL (VGPR stayed 84): compiler remats
// weights every step (reload f32 + re-convert, ~300 VALU/step).
// NOTE (R11): remat made cheap instead of fought: each block packs fp16
// fragment planes into LDS once (identical RNE conversions -> bit-identical
// results); per-step weight reads are ds_read_b128/b64, 16B/lane contiguous
// (conflict-free), zero conversion VALU.

struct TrueT  { static constexpr bool value = true;  };
struct FalseT { static constexpr bool value = false; };

typedef _Float16 v8hf __attribute__((ext_vector_type(8)));
typedef _Float16 v4hf __attribute__((ext_vector_type(4)));
typedef _Float16 v2hf __attribute__((ext_vector_type(2)));
typedef float    v4f  __attribute__((ext_vector_type(4)));

__device__ __forceinline__ v2hf pkrtz(float a, float b) {
    return __builtin_bit_cast(v2hf, __builtin_amdgcn_cvt_pkrtz(a, b));
}
__device__ __forceinline__ unsigned pack2(_Float16 a, _Float16 b) {
    v2hf v; v[0] = a; v[1] = b;
    return __builtin_bit_cast(unsigned, v);
}

__device__ __forceinline__ float rcp_(float x) { return __builtin_amdgcn_rcpf(x); }
__device__ __forceinline__ float sigf(float x) { return rcp_(1.0f + __expf(-x)); }
__device__ __forceinline__ float tanhf_(float x) {
    float e = __expf(2.0f * x);
    return 1.0f - 2.0f * rcp_(e + 1.0f);   // saturates correctly (rcp(inf)=0)
}

template<bool F32>
__device__ __forceinline__ float ldin(const void* p, long i) {
    if constexpr (F32) return ((const float*)p)[i];
    else               return __bfloat162float(((const __hip_bfloat16*)p)[i]);
}
template<bool F32>
__device__ __forceinline__ void stout(void* p, long i, float v) {
    if constexpr (F32) ((float*)p)[i] = v;
    else               ((__hip_bfloat16*)p)[i] = __float2bfloat16(v);
}

// MFMA wrappers. K16 legacy builtin guarded: the K32 fallback with zero-padded
// element slots is exactly equivalent (A/B share the (lane,elem)->k labeling).
__device__ __forceinline__ v4f mfma_k32(v8hf a, v8hf b, v4f c) {
    return __builtin_amdgcn_mfma_f32_16x16x32_f16(a, b, c, 0, 0, 0);
}
__device__ __forceinline__ v4f mfma_k16(v4hf a, v4hf b, v4f c) {
#if __has_builtin(__builtin_amdgcn_mfma_f32_16x16x16f16)
    return __builtin_amdgcn_mfma_f32_16x16x16f16(a, b, c, 0, 0, 0);
#else
    v8hf a8; v8hf b8;
    #pragma unroll
    for (int j = 0; j < 4; ++j) { a8[j] = a[j]; b8[j] = b[j]; }
    #pragma unroll
    for (int j = 4; j < 8; ++j) { a8[j] = (_Float16)0.f; b8[j] = (_Float16)0.f; }
    return __builtin_amdgcn_mfma_f32_16x16x32_f16(a8, b8, c, 0, 0, 0);
#endif
}

// ---- prep body (templated on dtype), writes permuted rows ----
template<bool F32>
__device__ __forceinline__ void prep_body(const void* W_in, const void* b_in,
                                          const void* W_out, const void* b_out,
                                          const void* W_ih, const void* W_hh,
                                          const void* b_ih, const void* b_hh,
                                          float* ws, int j)
{
    if (j >= 128) return;
    const int gate = j >> 5;
    const int u    = j & 31;
    const int qb   = u >> 3;
    const int psi  = u & 7;
    const int tt   = 2*gate + (psi >> 2);
    const int p    = 16*tt + 4*qb + (psi & 3);

    float wx[14];
    #pragma unroll
    for (int c = 0; c < 14; ++c) wx[c] = 0.0f;
    float bg = ldin<F32>(b_ih, j) + ldin<F32>(b_hh, j);
    #pragma unroll
    for (int m = 0; m < 32; ++m) {
        float wihm = ldin<F32>(W_ih, j*32 + m);
        #pragma unroll
        for (int c = 0; c < 14; ++c) wx[c] = fmaf(wihm, ldin<F32>(W_in, m*14 + c), wx[c]);
        bg = fmaf(wihm, ldin<F32>(b_in, m), bg);
    }
    float a0 = wx[0];
    #pragma unroll
    for (int k = 0; k < 32; ++k)
        ws[p*32 + k] = ldin<F32>(W_hh, j*32 + k) + a0 * ldin<F32>(W_out, k);
    float bo = ldin<F32>(b_out, 0);
    const float bg2 = bg + a0 * bo;
    #pragma unroll
    for (int f = 0; f < 16; ++f)
        ws[4096 + p*16 + f] = (f < 13) ? wx[1 + f] : (f == 13 ? bg2 : 0.0f);
    ws[6272 + p] = a0;
    if (j < 32) ws[6528 + j] = ldin<F32>(W_out, j);   // unit-indexed
    if (j == 0) ws[6560] = bo;
}

// ---- fused detect + prep: one launch ----
__global__ void prep_all(const unsigned short* __restrict__ feat_raw,
                         const void* __restrict__ W_in,  const void* __restrict__ b_in,
                         const void* __restrict__ W_out, const void* __restrict__ b_out,
                         const void* __restrict__ W_ih,  const void* __restrict__ W_hh,
                         const void* __restrict__ b_ih,  const void* __restrict__ b_hh,
                         float* __restrict__ ws)
{
    __shared__ int cnt;
    const int tid = threadIdx.x;   // 0..127
    if (tid == 0) cnt = 0;
    __syncthreads();
    int insane = 0;
    for (int i = tid; i < 4096; i += 128) {
        float v = __uint_as_float(((unsigned int)feat_raw[i]) << 16);
        if (!(fabsf(v) < 1e8f)) insane++;
    }
    if (insane) atomicAdd(&cnt, insane);
    __syncthreads();
    const bool f32 = (cnt > 8);
    if (tid == 0) ws[FLAG_OFF] = f32 ? 1.0f : 0.0f;
    if (f32) prep_body<true >(W_in,b_in,W_out,b_out,W_ih,W_hh,b_ih,b_hh,ws,tid);
    else     prep_body<false>(W_in,b_in,W_out,b_out,W_ih,W_hh,b_ih,b_hh,ws,tid);
}

// ---- main LSTM body: h recirculates in-register; weights in LDS as packed
// fp16 fragment planes (per tile tt, stride 768 u32):
//   +0 whi0[lane*4] (uint4=v8hf)  +256 wlo0[lane*4]
//   +512 whi1[lane*2] (uint2=v4hf) +640 wlo1[lane*2]
// Reads are 16B/lane (8B for k16) contiguous -> conflict-free ds_read.
template<bool F32>
__device__ __forceinline__ void lstm_body(const void* __restrict__ pm25,
                                          const void* __restrict__ feat,
                                          const float* __restrict__ ws,
                                          void* __restrict__ out)
{
    __shared__ __align__(16) unsigned sfrag[6144];   // 24 KB
    const int tid  = threadIdx.x;
    const int lane = tid & 63;
    const int rho  = lane & 15;      // seq within wave / A-row / D-col
    const int q    = lane >> 4;      // k-block / D-row-block / unit-block
    const int wv   = tid >> 6;
    const int wseq = (blockIdx.x*4 + wv) * 16;
    const int seq  = wseq + rho;
    const int bb   = seq / CITY_;
    const int city = seq - bb*CITY_;

    // ---- pack fp16 fragment planes into LDS (once per block).  RNE
    // conversions identical to the per-wave register path -> bit-identical.
    {
        const int L  = tid & 63;
        const int r2 = L & 15, q2 = L >> 4;
        #pragma unroll
        for (int k = 0; k < 2; ++k) {
            const int tt = (tid >> 6) * 2 + k;          // waves 0..3 x 2 tiles
            const float* src = ws + (16*tt + r2)*32 + 8*q2;
            unsigned* d0 = sfrag + tt*768 + L*4;
            #pragma unroll
            for (int m = 0; m < 4; ++m) {
                const float wA = src[2*m], wB = src[2*m+1];
                const _Float16 hA = (_Float16)wA, hB = (_Float16)wB;
                d0[m] = pack2(hA, hB);
                if constexpr (F32) {
                    (sfrag + tt*768 + 256 + L*4)[m] =
                        pack2((_Float16)(wA - (float)hA), (_Float16)(wB - (float)hB));
                }
            }
            const float* srcf = ws + 4096 + (16*tt + r2)*16 + 4*q2;
            unsigned* d2 = sfrag + tt*768 + 512 + L*2;
            #pragma unroll
            for (int m = 0; m < 2; ++m) {
                const float wA = srcf[2*m], wB = srcf[2*m+1];
                const _Float16 hA = (_Float16)wA, hB = (_Float16)wB;
                d2[m] = pack2(hA, hB);
                if constexpr (F32) {
                    (sfrag + tt*768 + 640 + L*2)[m] =
                        pack2((_Float16)(wA - (float)hA), (_Float16)(wB - (float)hB));
                }
            }
        }
    }
    __syncthreads();

    float wo8[8];
    #pragma unroll
    for (int j = 0; j < 8; ++j) wo8[j] = ws[6528 + 8*q + j]; // wout[unit 8q+j]
    const float bo = ws[6560];
    const long obase = (long)bb*PRED_*CITY_ + city;

    // ---- per-lane direct feature loads: elems 4q..4q+3.
    // elem 13 = constant 1.0 (bias column); 14,15 = 0.
    long fbase = ((long)(bb*(HIST_+PRED_) + HIST_)*CITY_ + city)*FEAT_;
    float fn[4];
    auto ldfeat = [&]() {            // prefetch one step's 4 elems into regs
        #pragma unroll
        for (int j = 0; j < 4; ++j) {
            const int e = 4*q + j;
            fn[j] = (e < FEAT_) ? ldin<F32>(feat, fbase + e)
                                : (e == FEAT_ ? 1.0f : 0.0f);
        }
        fbase += CITY_ * FEAT_;
    };
    v4hf fhi, flo;
    auto convf = [&]() {             // fn (raw) -> fp16 fragment(s)
        #pragma unroll
        for (int jj = 0; jj < 2; ++jj) {
            const v2hf ph = pkrtz(fn[2*jj], fn[2*jj+1]);
            fhi[2*jj] = ph[0]; fhi[2*jj+1] = ph[1];
            if constexpr (F32) {
                const v2hf pl = pkrtz(fn[2*jj] - (float)ph[0],
                                      fn[2*jj+1] - (float)ph[1]);
                flo[2*jj] = pl[0]; flo[2*jj+1] = pl[1];
            }
        }
    };

    float cst[8];                    // c-state, units 8q+psi, seq rho
    v8hf  xhi, xlo;                  // h: next step's B chunk0 (in-lane!)

    auto finishT = [&](v4f (&acc)[8], int t, auto T0flag) {
        constexpr bool T0 = decltype(T0flag)::value;
        // psi = 4*(tt&1)+r: i=acc[tl], f=acc[2+tl], g=acc[4+tl], o=acc[6+tl]
        float h[8];
        #pragma unroll
        for (int psi = 0; psi < 8; ++psi) {
            const int tl = psi >> 2, r = psi & 3;
            const float I = sigf(acc[tl][r]);
            const float G = tanhf_(acc[4+tl][r]);
            const float O = sigf(acc[6+tl][r]);
            float c;
            if constexpr (T0) c = I*G;
            else              c = fmaf(sigf(acc[2+tl][r]), cst[psi], I*G);
            cst[psi] = c;
            h[psi] = O * tanhf_(c);
        }
        #pragma unroll
        for (int jj = 0; jj < 4; ++jj) {   // pack -> next B fragment
            const v2hf ph = pkrtz(h[2*jj], h[2*jj+1]);
            xhi[2*jj] = ph[0]; xhi[2*jj+1] = ph[1];
            if constexpr (F32) {           // lo exactly compensates RTZ
                const v2hf pl = pkrtz(h[2*jj] - (float)ph[0],
                                      h[2*jj+1] - (float)ph[1]);
                xlo[2*jj] = pl[0]; xlo[2*jj+1] = pl[1];
            }
        }
        float y = 0.0f;                    // y_t = wout . h + bout
        #pragma unroll
        for (int psi = 0; psi < 8; ++psi) y = fmaf(wo8[psi], h[psi], y);
        y += __shfl_xor(y, 16);
        y += __shfl_xor(y, 32);
        if (q == 0) stout<F32>(out, obase + (long)t*CITY_, y + bo);
    };

    // ---- t = 0 : gates = a0*(x0-bo) (C-init) + Wf.[feat;1]  (h0 = 0) ----
    ldfeat();            // fn = feats(0)
    convf();             // fhi = feats(0)
    ldfeat();            // fn = feats(1) in flight
    {
        const float x0 = ldin<F32>(pm25, (long)(bb*HIST_ + (HIST_-1))*CITY_ + city);
        const float x0b = x0 - bo;
        v4f acc[8];
        #pragma unroll
        for (int tt = 0; tt < 8; ++tt) {
            const v4f a0 = *(const v4f*)(ws + 6272 + 16*tt + 4*q);
            v4f c;
            #pragma unroll
            for (int r = 0; r < 4; ++r) c[r] = a0[r] * x0b;
            const v4hf whi1 = __builtin_bit_cast(
                v4hf, *(const uint2*)(sfrag + tt*768 + 512 + lane*2));
            v4f a = mfma_k16(whi1, fhi, c);
            if constexpr (F32) {
                const v4hf wlo1 = __builtin_bit_cast(
                    v4hf, *(const uint2*)(sfrag + tt*768 + 640 + lane*2));
                a = mfma_k16(wlo1, fhi, a);
                a = mfma_k16(whi1, flo, a);
            }
            acc[tt] = a;
        }
        finishT(acc, 0, TrueT{});
    }

    // ---- t = 1..23 ----
    const v4f zacc = {0.0f, 0.0f, 0.0f, 0.0f};
    #pragma unroll 1
    for (int t = 1; t < PRED_; ++t) {
        convf();                        // fhi = feats(t) (loaded last iter)
        if (t < PRED_-1) ldfeat();      // fn = feats(t+1)
        v4f acc[8];
        #pragma unroll
        for (int tt = 0; tt < 8; ++tt) {
            const v8hf whi0 = __builtin_bit_cast(
                v8hf, *(const uint4*)(sfrag + tt*768 + lane*4));
            const v4hf whi1 = __builtin_bit_cast(
                v4hf, *(const uint2*)(sfrag + tt*768 + 512 + lane*2));
            v4f a = mfma_k32(whi0, xhi, zacc);
            if constexpr (F32) {
                const v8hf wlo0 = __builtin_bit_cast(
                    v8hf, *(const uint4*)(sfrag + tt*768 + 256 + lane*4));
                a = mfma_k32(wlo0, xhi, a);
                a = mfma_k32(whi0, xlo, a);
            }
            a = mfma_k16(whi1, fhi, a);
            if constexpr (F32) {
                const v4hf wlo1 = __builtin_bit_cast(
                    v4hf, *(const uint2*)(sfrag + tt*768 + 640 + lane*2));
                a = mfma_k16(wlo1, fhi, a);
                a = mfma_k16(whi1, flo, a);
            }
            acc[tt] = a;
        }
        finishT(acc, t, FalseT{});
    }
}

// bf16 kernel: lean path, cap 170 (3 waves/EU min); LDS 3x24KB = 72KB/CU ok.
__global__ __launch_bounds__(256, 3) void lstm_bf16(
    const void* __restrict__ pm25, const void* __restrict__ feat,
    const float* __restrict__ ws,  void* __restrict__ out)
{
    if (ws[FLAG_OFF] != 0.0f) return;
    lstm_body<false>(pm25, feat, ws, out);
}

// fp32 kernel: hi/lo path, cap 256; LDS 2x24KB = 48KB/CU ok.
__global__ __launch_bounds__(256, 2) void lstm_f32(
    const void* __restrict__ pm25, const void* __restrict__ feat,
    const float* __restrict__ ws,  void* __restrict__ out)
{
    if (ws[FLAG_OFF] != 1.0f) return;
    lstm_body<true>(pm25, feat, ws, out);
}

extern "C" void kernel_launch(void* const* d_in, const int* in_sizes, int n_in,
                              void* d_out, int out_size, void* d_ws, size_t ws_size,
                              hipStream_t stream) {
    const void* pm25  = d_in[0];
    const void* feat  = d_in[1];
    const void* W_in  = d_in[2];
    const void* b_in  = d_in[3];
    const void* W_out = d_in[4];
    const void* b_out = d_in[5];
    const void* W_ih  = d_in[6];
    const void* W_hh  = d_in[7];
    const void* b_ih  = d_in[8];
    const void* b_hh  = d_in[9];
    float* ws = (float*)d_ws;

    prep_all<<<dim3(1), dim3(128), 0, stream>>>(
        (const unsigned short*)feat, W_in, b_in, W_out, b_out,
        W_ih, W_hh, b_ih, b_hh, ws);

    lstm_bf16<<<dim3(BC_/64), dim3(256), 0, stream>>>(pm25, feat, ws, d_out);
    lstm_f32 <<<dim3(BC_/64), dim3(256), 0, stream>>>(pm25, feat, ws, d_out);
}